// Round 5
// baseline (129.918 us; speedup 1.0000x reference)
//
#include <hip/hip_runtime.h>
#include <hip/hip_bf16.h>

#define N_NODES 50000
#define N_EDGES 800000
#define FEAT 64
#define NRELS 8
#define NBUCK 391         // ceil(50000/128) buckets of 128 dst nodes (dst >> 7)
#define NBP 196           // bfill binning blocks (4096 edges each)
#define BCAP 2816         // fixed slots per bucket (mean 2048 + 17 sigma)
#define FB_BLOCKS 782     // ceil(N / 64) feat->bf16 rider blocks (in bfill)
#define NPB 32            // dst nodes per fuse block
#define FUSE_BLOCKS 1563  // ceil(N / NPB)

typedef __attribute__((ext_vector_type(8))) short bf16x8;   // 8 bf16 in 4 VGPRs
typedef __attribute__((ext_vector_type(4))) float f32x4;

static __host__ __device__ inline size_t align256(size_t x) { return (x + 255) & ~(size_t)255; }

__device__ inline unsigned short f2b(float f) {   // fp32 -> bf16 RNE
    unsigned u = __builtin_bit_cast(unsigned, f);
    unsigned r = (u + 0x7fffu + ((u >> 16) & 1u)) >> 16;
    return (unsigned short)r;
}
__device__ inline float b2f(unsigned short u) {   // bf16 -> fp32
    unsigned v = ((unsigned)u) << 16;
    return __builtin_bit_cast(float, v);
}

// ---------------------------------------------------------------------------
// Kernel 1: blocks [0,NBP) = bucket fill (fixed-capacity regions,
// entry = src|et<<16|dlo<<19, dlo = dst&127, bucket = dst>>7);
// blocks [NBP, NBP+FB_BLOCKS) = feat->bf16 (Fb) rider; first 32 riders also
// build WtT[r][f][d] = bf16(W[r][d][f]).
// ---------------------------------------------------------------------------
__global__ void bfill_kernel(const int* __restrict__ dst, const int* __restrict__ srcv,
                             const int* __restrict__ et, const float* __restrict__ W,
                             const float* __restrict__ feat,
                             int* __restrict__ bcnt, int* __restrict__ tmp,
                             unsigned short* __restrict__ WtT,
                             unsigned short* __restrict__ Fb, int E, int N) {
    const int t = threadIdx.x;

    if (blockIdx.x >= NBP) {
        // ------------- Fb rider (+ WtT on first 32 blocks) -------------
        const int fbb = blockIdx.x - NBP;
        if (fbb < 32) {
            int i4 = fbb * 256 + t;           // [0, 8192) float4s of W
            float4 v = ((const float4*)W)[i4];
            int bse = i4 * 4;                 // flat element = (r*64+d)*64 + f
            int f0 = bse & 63;
            int rd = bse >> 6;                // r*64 + d
            int d  = rd & 63;
            int r  = rd >> 6;
            unsigned short* w0 = WtT + ((size_t)(r * 64 + f0) * 64 + d);
            w0[0 * 64] = f2b(v.x);
            w0[1 * 64] = f2b(v.y);
            w0[2 * 64] = f2b(v.z);
            w0[3 * 64] = f2b(v.w);
        }
        const int node = fbb * 64 + (t >> 2);
        if (node >= N) return;
        const int seg = t & 3;
        const float4* F4 = (const float4*)feat + (size_t)node * 16 + seg * 4;
        float4 v0 = F4[0], v1 = F4[1], v2 = F4[2], v3 = F4[3];
        bf16x8 b0, b1;
        b0[0] = (short)f2b(v0.x); b0[1] = (short)f2b(v0.y);
        b0[2] = (short)f2b(v0.z); b0[3] = (short)f2b(v0.w);
        b0[4] = (short)f2b(v1.x); b0[5] = (short)f2b(v1.y);
        b0[6] = (short)f2b(v1.z); b0[7] = (short)f2b(v1.w);
        b1[0] = (short)f2b(v2.x); b1[1] = (short)f2b(v2.y);
        b1[2] = (short)f2b(v2.z); b1[3] = (short)f2b(v2.w);
        b1[4] = (short)f2b(v3.x); b1[5] = (short)f2b(v3.y);
        b1[6] = (short)f2b(v3.z); b1[7] = (short)f2b(v3.w);
        *(bf16x8*)(Fb + (size_t)node * 64 + seg * 16)     = b0;
        *(bf16x8*)(Fb + (size_t)node * 64 + seg * 16 + 8) = b1;
        return;
    }

    // ------------- edge binning half -------------
    __shared__ int hist[392];
    __shared__ int base[392];
    __shared__ int lcur[392];
    for (int j = t; j < 392; j += 256) { hist[j] = 0; lcur[j] = 0; }
    __syncthreads();

    const int4* dst4 = (const int4*)dst;
    const int4* src4 = (const int4*)srcv;
    const int4* et4  = (const int4*)et;
    const int n4 = E >> 2;                    // E % 4 == 0
    int bk[16], pk[16];
#pragma unroll
    for (int k = 0; k < 4; k++) {
        int i4 = blockIdx.x * 1024 + t + k * 256;
        if (i4 < n4) {
            int4 d = dst4[i4];
            int4 s = src4[i4];
            int4 r = et4[i4];
            const int dd[4] = {d.x, d.y, d.z, d.w};
            const int ss[4] = {s.x, s.y, s.z, s.w};
            const int rr[4] = {r.x, r.y, r.z, r.w};
#pragma unroll
            for (int j = 0; j < 4; j++) {
                int idx = k * 4 + j;
                bk[idx] = dd[j] >> 7;
                pk[idx] = (ss[j] & 0xFFFF) | (rr[j] << 16) | ((dd[j] & 127) << 19);
                atomicAdd(&hist[bk[idx]], 1);
            }
        } else {
#pragma unroll
            for (int j = 0; j < 4; j++) bk[k * 4 + j] = -1;
        }
    }
    __syncthreads();
    for (int j = t; j < NBUCK; j += 256)
        if (hist[j] > 0)
            base[j] = j * BCAP + atomicAdd(&bcnt[j], hist[j]);
    __syncthreads();
#pragma unroll
    for (int k = 0; k < 16; k++) {
        if (bk[k] >= 0) {
            int r = atomicAdd(&lcur[bk[k]], 1);
            int pos = base[bk[k]] + r;
            if (pos < (bk[k] + 1) * BCAP)   // memory-safety clamp (never hit)
                tmp[pos] = pk[k];
        }
    }
}

// ---------------------------------------------------------------------------
// Kernel 2: per-bucket counting sort by bin = dlo*8 + rel (1024 bins,
// 128-node buckets) -> edges of a node are rel-contiguous. 391 blocks.
// ---------------------------------------------------------------------------
__global__ void mid_kernel(const int* __restrict__ bcnt, const int* __restrict__ tmp,
                           int* __restrict__ spk, int* __restrict__ off_s,
                           int* __restrict__ off_e, int N) {
    __shared__ int hist[1024];
    __shared__ int s[256];
    const int t = threadIdx.x;

    const int b = blockIdx.x;
    const int n0 = b * 128;
    const int nn = min(128, N - n0);
    const int s0 = b * BCAP;
    const int s1 = s0 + min(bcnt[b], BCAP);

    *(int4*)&hist[t * 4] = make_int4(0, 0, 0, 0);
    __syncthreads();
    // count pass, 4x unrolled for MLP
    for (int i = s0 + t; i < s1; i += 1024) {
        int v0 = tmp[i];
        int v1 = (i + 256 < s1) ? tmp[i + 256] : -1;
        int v2 = (i + 512 < s1) ? tmp[i + 512] : -1;
        int v3 = (i + 768 < s1) ? tmp[i + 768] : -1;
        atomicAdd(&hist[(v0 >> 16) & 1023], 1);
        if (v1 >= 0) atomicAdd(&hist[(v1 >> 16) & 1023], 1);
        if (v2 >= 0) atomicAdd(&hist[(v2 >> 16) & 1023], 1);
        if (v3 >= 0) atomicAdd(&hist[(v3 >> 16) & 1023], 1);
    }
    __syncthreads();
    // two-level scan: thread t owns bins [4t, 4t+4) = half of node (t>>1)'s rels
    int loc[4], st4[4], T = 0;
#pragma unroll
    for (int j = 0; j < 4; j++) loc[j] = hist[t * 4 + j];
#pragma unroll
    for (int j = 0; j < 4; j++) { st4[j] = T; T += loc[j]; }
    s[t] = T;
    __syncthreads();
    for (int o = 1; o < 256; o <<= 1) {
        int u = (t >= o) ? s[t - o] : 0;
        __syncthreads();
        s[t] += u;
        __syncthreads();
    }
    const int ex = s[t] - T;              // exclusive prefix over threads
    {
        const int n = t >> 1;
        if (n < nn) {
            if ((t & 1) == 0) off_s[n0 + n] = s0 + ex;
            else              off_e[n0 + n] = s0 + ex + T;
        }
    }
#pragma unroll
    for (int j = 0; j < 4; j++) hist[t * 4 + j] = s0 + ex + st4[j];
    __syncthreads();
    // scatter pass, 4x unrolled
    for (int i = s0 + t; i < s1; i += 1024) {
        int v0 = tmp[i];
        int v1 = (i + 256 < s1) ? tmp[i + 256] : -1;
        int v2 = (i + 512 < s1) ? tmp[i + 512] : -1;
        int v3 = (i + 768 < s1) ? tmp[i + 768] : -1;
        int p0 = atomicAdd(&hist[(v0 >> 16) & 1023], 1);
        spk[p0] = v0;
        if (v1 >= 0) { int p1 = atomicAdd(&hist[(v1 >> 16) & 1023], 1); spk[p1] = v1; }
        if (v2 >= 0) { int p2 = atomicAdd(&hist[(v2 >> 16) & 1023], 1); spk[p2] = v2; }
        if (v3 >= 0) { int p3 = atomicAdd(&hist[(v3 >> 16) & 1023], 1); spk[p3] = v3; }
    }
}

// ---------------------------------------------------------------------------
// Kernel 3: fused gather-sum -> per-relation MFMA -> epilogue.
// v3 gather: lane-parallel pk preload, shfl-at-use 8-slot refill ring
// (slim VGPR -> 5 blocks/CU), tiered 8-edge chunks skip work for low deg,
// epilogue feat prefetched at entry. deg > 32 handled by serial tail.
// ---------------------------------------------------------------------------
__global__ __launch_bounds__(256, 4) void fuse_kernel(
    const int* __restrict__ off_s, const int* __restrict__ off_e,
    const int* __restrict__ spk, const unsigned short* __restrict__ Fb,
    const unsigned short* __restrict__ WtT, const float* __restrict__ feat,
    float* __restrict__ out, int N) {
    __shared__ unsigned short Sb[NRELS][NPB][64];   // 32768 B, swizzled d-blocks
    const int t = threadIdx.x;
    const int n0 = blockIdx.x * NPB;
    const int nn = min(NPB, N - n0);
    const int gid = t >> 3, q = t & 7;              // group gid = node, lane q = d-block
    const int lanebase = (t & 63) & ~7;             // group's lane-0 within wave

    // Node range (also reused by the epilogue: epilogue node == gid).
    int b = 0, e = 0;
    if (gid < nn) {
        const int gn = n0 + gid;
        b = off_s[gn];
        e = off_e[gn];
    }

    // Epilogue feat prefetch (hides the fp32 residual load under the gather).
    float4 h0e = make_float4(0.f, 0.f, 0.f, 0.f), h1e = h0e;
    const int ef0 = q * 8;
    if (gid < nn) {
        const float4* fp = (const float4*)feat + (size_t)(n0 + gid) * 16 + (ef0 >> 2);
        h0e = fp[0];
        h1e = fp[1];
    }

    // Zero S (covers nodes/rels with no edges).
    {
        f32x4 z = {0.f, 0.f, 0.f, 0.f};
        f32x4* zp = (f32x4*)&Sb[0][0][0];
#pragma unroll
        for (int i = 0; i < 8; i++) zp[t + 256 * i] = z;
    }
    __syncthreads();

    // ---- gather ----
    if (gid < nn && b < e) {
        const int swz = (q ^ (gid & 7)) * 8;        // physical slot of logical block q
        unsigned short* srow = &Sb[0][0][0] + (size_t)gid * 64 + swz;
        float a[8] = {0.f, 0.f, 0.f, 0.f, 0.f, 0.f, 0.f, 0.f};
        int curR = -1;

        auto flushS = [&](int rel) {
            bf16x8 v;
#pragma unroll
            for (int k = 0; k < 8; k++) v[k] = (short)f2b(a[k]);
            *(bf16x8*)(srow + (size_t)rel * (NPB * 64)) = v;
        };

        // Lane-parallel pk preload: lane q holds edges b+q+8k, k=0..3.
        int pks[4];
#pragma unroll
        for (int k = 0; k < 4; k++)
            pks[k] = (b + q + 8 * k < e) ? spk[b + q + 8 * k] : -1;

        // 8-slot ring, shfl-at-use refill.
        bf16x8 u[8];
        int pkv[8];
#pragma unroll
        for (int j = 0; j < 8; j++) {
            int pk = __shfl(pks[0], lanebase | j);
            pkv[j] = pk;
            u[j] = (bf16x8){0, 0, 0, 0, 0, 0, 0, 0};
            if (pk >= 0)
                u[j] = *(const bf16x8*)(Fb + (size_t)(pk & 0xFFFF) * 64 + q * 8);
        }
#pragma unroll
        for (int tier = 0; tier < 4; tier++) {
            if (b + tier * 8 >= e) break;           // group-uniform skip
#pragma unroll
            for (int jj = 0; jj < 8; jj++) {
                const int j = tier * 8 + jj;
                bf16x8 uu = u[jj];
                int pk = pkv[jj];
                if (tier < 3) {                     // refill slot jj with edge j+8
                    int pkn = __shfl(pks[(j + 8) >> 3], lanebase | jj);
                    pkv[jj] = pkn;
                    if (pkn >= 0)
                        u[jj] = *(const bf16x8*)(Fb + (size_t)(pkn & 0xFFFF) * 64 + q * 8);
                }
                if (pk >= 0) {
                    int rel = (pk >> 16) & 7;
                    if (rel != curR) {
                        if (curR >= 0) flushS(curR);
                        curR = rel;
#pragma unroll
                        for (int k = 0; k < 8; k++) a[k] = b2f((unsigned short)uu[k]);
                    } else {
#pragma unroll
                        for (int k = 0; k < 8; k++) a[k] += b2f((unsigned short)uu[k]);
                    }
                }
            }
        }
        // Rare serial tail (deg > 32).
        for (int i = b + 32; i < e; i++) {
            int pk = spk[i];
            bf16x8 uu = *(const bf16x8*)(Fb + (size_t)(pk & 0xFFFF) * 64 + q * 8);
            int rel = (pk >> 16) & 7;
            if (rel != curR) {
                if (curR >= 0) flushS(curR);
                curR = rel;
#pragma unroll
                for (int k = 0; k < 8; k++) a[k] = b2f((unsigned short)uu[k]);
            } else {
#pragma unroll
                for (int k = 0; k < 8; k++) a[k] += b2f((unsigned short)uu[k]);
            }
        }
        if (curR >= 0) flushS(curR);
    }
    __syncthreads();

    // ---- MFMA: C[n][f] = sum_r S_r[n][:] @ W_r[:][f]. S is bf16.
    const int w = t >> 6, l = t & 63, col = l & 15, quad = l >> 4;
    f32x4 acc0 = {0.f, 0.f, 0.f, 0.f}, acc1 = {0.f, 0.f, 0.f, 0.f};
    const int sw0 = (quad ^ (col & 7)) * 8;           // logical k-block quad
    const int sw1 = ((quad + 4) ^ (col & 7)) * 8;     // logical k-block quad+4
#pragma unroll
    for (int r = 0; r < NRELS; r++) {
        const unsigned short* wp = WtT + (size_t)r * 4096 + ((w * 16 + col) * 64 + quad * 8);
        bf16x8 b0 = *(const bf16x8*)wp;               // W frags from L2 (hot)
        bf16x8 b1 = *(const bf16x8*)(wp + 32);
        const unsigned short* Sr = &Sb[0][0][0] + (size_t)r * (NPB * 64);
        bf16x8 a0 = *(const bf16x8*)&Sr[col * 64 + sw0];
        bf16x8 a1 = *(const bf16x8*)&Sr[col * 64 + sw1];
        bf16x8 c0 = *(const bf16x8*)&Sr[(16 + col) * 64 + sw0];
        bf16x8 c1 = *(const bf16x8*)&Sr[(16 + col) * 64 + sw1];
        acc0 = __builtin_amdgcn_mfma_f32_16x16x32_bf16(a0, b0, acc0, 0, 0, 0);
        acc0 = __builtin_amdgcn_mfma_f32_16x16x32_bf16(a1, b1, acc0, 0, 0, 0);
        acc1 = __builtin_amdgcn_mfma_f32_16x16x32_bf16(c0, b0, acc1, 0, 0, 0);
        acc1 = __builtin_amdgcn_mfma_f32_16x16x32_bf16(c1, b1, acc1, 0, 0, 0);
    }
    __syncthreads();   // all S reads done -> alias Sb as C bounce [32][72] f32

    float* C = (float*)&Sb[0][0][0];
#pragma unroll
    for (int i = 0; i < 4; i++) {
        C[(quad * 4 + i) * 72 + w * 16 + col]        = acc0[i];
        C[(16 + quad * 4 + i) * 72 + w * 16 + col]   = acc1[i];
    }
    __syncthreads();

    // ---- epilogue: thread t -> node gid (= t>>3), f-block q (coalesced).
    if (gid < nn) {
        const int gn = n0 + gid;
        const int deg = e - b;
        float4 m0 = *(const float4*)&C[gid * 72 + ef0];
        float4 m1 = *(const float4*)&C[gid * 72 + ef0 + 4];
        float4 r0, r1;
        if (deg > 0) {
            float inv = 0.8f / (float)deg;
            r0.x = fmaxf(0.2f * h0e.x + m0.x * inv, 0.f);
            r0.y = fmaxf(0.2f * h0e.y + m0.y * inv, 0.f);
            r0.z = fmaxf(0.2f * h0e.z + m0.z * inv, 0.f);
            r0.w = fmaxf(0.2f * h0e.w + m0.w * inv, 0.f);
            r1.x = fmaxf(0.2f * h1e.x + m1.x * inv, 0.f);
            r1.y = fmaxf(0.2f * h1e.y + m1.y * inv, 0.f);
            r1.z = fmaxf(0.2f * h1e.z + m1.z * inv, 0.f);
            r1.w = fmaxf(0.2f * h1e.w + m1.w * inv, 0.f);
        } else {
            r0 = h0e; r1 = h1e;
        }
        float4* op = (float4*)out + (size_t)gn * 16 + (ef0 >> 2);
        op[0] = r0;
        op[1] = r1;
    }
}

// ---------------------------------------------------------------------------
// Fallback kernels (small workspace): on-the-fly transform + atomics (fp32).
// ---------------------------------------------------------------------------
__global__ void degf_kernel(const int* __restrict__ dst, float* __restrict__ deg, int E) {
    int e = blockIdx.x * blockDim.x + threadIdx.x;
    if (e < E) atomicAdd(deg + dst[e], 1.0f);
}

__global__ void otf_kernel(const int* __restrict__ src, const int* __restrict__ dst,
                           const int* __restrict__ et, const float* __restrict__ feat,
                           const float* __restrict__ W, float* __restrict__ out, int E) {
    int wid = (blockIdx.x * blockDim.x + threadIdx.x) >> 6;
    int l = threadIdx.x & 63;
    if (wid >= E) return;
    int s = src[wid], dd = dst[wid], r = et[wid];
    float fv = feat[(size_t)s * 64 + l];
    const float* Wr = W + (size_t)r * 4096;
    float acc = 0.f;
#pragma unroll
    for (int d = 0; d < 64; d++) {
        float a = __shfl(fv, d);
        acc += a * Wr[d * 64 + l];
    }
    atomicAdd(out + (size_t)dd * 64 + l, acc);
}

__global__ void final_kernel(const float* __restrict__ feat, const float* __restrict__ deg,
                             float* __restrict__ out, int N) {
    int i = blockIdx.x * blockDim.x + threadIdx.x;
    if (i >= N * 16) return;
    int n = i >> 4;
    float d = deg[n];
    float4 f = ((const float4*)feat)[i];
    float4 m = ((float4*)out)[i];
    float4 res;
    if (d > 0.f) {
        float inv = 0.8f / d;
        res.x = fmaxf(0.2f * f.x + m.x * inv, 0.f);
        res.y = fmaxf(0.2f * f.y + m.y * inv, 0.f);
        res.z = fmaxf(0.2f * f.z + m.z * inv, 0.f);
        res.w = fmaxf(0.2f * f.w + m.w * inv, 0.f);
    } else {
        res = f;
    }
    ((float4*)out)[i] = res;
}

extern "C" void kernel_launch(void* const* d_in, const int* in_sizes, int n_in,
                              void* d_out, int out_size, void* d_ws, size_t ws_size,
                              hipStream_t stream) {
    const float* feat = (const float*)d_in[0];   // [N, 64]
    const float* W    = (const float*)d_in[1];   // [8, 64, 64]
    const int*   src  = (const int*)d_in[2];     // [E]
    const int*   dst  = (const int*)d_in[3];     // [E]
    const int*   et   = (const int*)d_in[4];     // [E]
    float* out = (float*)d_out;                  // [N, 64]

    const int N = N_NODES, E = N_EDGES;

    // Workspace layout:
    char* p = (char*)d_ws;
    int* bcnt  = (int*)p;  p += align256((size_t)NBUCK * 4);
    int* off_s = (int*)p;  p += align256((size_t)N * 4);
    int* off_e = (int*)p;  p += align256((size_t)N * 4);
    int* tmp   = (int*)p;  p += align256((size_t)NBUCK * BCAP * 4);   // 4.4 MB
    int* spk   = (int*)p;  p += align256((size_t)NBUCK * BCAP * 4);   // 4.4 MB
    unsigned short* WtT = (unsigned short*)p;
    p += align256((size_t)NRELS * FEAT * FEAT * 2);                   // 64 KB
    unsigned short* Fb = (unsigned short*)p;
    p += align256((size_t)N * FEAT * 2);                              // 6.4 MB
    size_t need_full = (size_t)(p - (char*)d_ws);

    if (ws_size >= need_full) {
        hipMemsetAsync(bcnt, 0, (size_t)NBUCK * 4, stream);
        bfill_kernel<<<NBP + FB_BLOCKS, 256, 0, stream>>>(dst, src, et, W, feat,
                                                          bcnt, tmp, WtT, Fb, E, N);
        mid_kernel<<<NBUCK, 256, 0, stream>>>(bcnt, tmp, spk, off_s, off_e, N);
        fuse_kernel<<<FUSE_BLOCKS, 256, 0, stream>>>(off_s, off_e, spk, Fb, WtT,
                                                     feat, out, N);
    } else {
        // Minimal-workspace fallback.
        float* deg = (float*)d_ws;
        hipMemsetAsync(out, 0, (size_t)N * FEAT * 4, stream);
        hipMemsetAsync(deg, 0, (size_t)N * 4, stream);
        degf_kernel<<<(E + 255) / 256, 256, 0, stream>>>(dst, deg, E);
        otf_kernel<<<(E + 3) / 4, 256, 0, stream>>>(src, dst, et, feat, W, out, E);
        final_kernel<<<(N * 16 + 255) / 256, 256, 0, stream>>>(feat, deg, out, N);
    }
}

// Round 6
// 124.967 us; speedup vs baseline: 1.0396x; 1.0396x over previous
//
#include <hip/hip_runtime.h>
#include <hip/hip_bf16.h>

#define N_NODES 50000
#define N_EDGES 800000
#define FEAT 64
#define NRELS 8
#define NPB 32            // dst nodes per bucket = per fuse block
#define NBUCK 1563        // ceil(50000/32) buckets (dst >> 5)
#define NBP 196           // bfill binning blocks (4096 edges each)
#define BCAP 768          // slots per bucket (mean 512 + 11 sigma)
#define FB_BLOCKS 782     // ceil(N / 64) feat->bf16 rider blocks (in bfill)

typedef __attribute__((ext_vector_type(8))) short bf16x8;   // 8 bf16 in 4 VGPRs
typedef __attribute__((ext_vector_type(4))) float f32x4;

static __host__ __device__ inline size_t align256(size_t x) { return (x + 255) & ~(size_t)255; }

__device__ inline unsigned short f2b(float f) {   // fp32 -> bf16 RNE
    unsigned u = __builtin_bit_cast(unsigned, f);
    unsigned r = (u + 0x7fffu + ((u >> 16) & 1u)) >> 16;
    return (unsigned short)r;
}
__device__ inline float b2f(unsigned short u) {   // bf16 -> fp32
    unsigned v = ((unsigned)u) << 16;
    return __builtin_bit_cast(float, v);
}

// ---------------------------------------------------------------------------
// Kernel 1: blocks [0,NBP) = bin edges into 32-node buckets (bucket = dst>>5,
// entry pk = src | et<<16 | (dst&31)<<19 -> sort key (pk>>16)&255 = node*8+rel);
// blocks [NBP, NBP+FB_BLOCKS) = feat->bf16 (Fb) rider; first 32 riders also
// build WtT[r][f][d] = bf16(W[r][d][f]).
// ---------------------------------------------------------------------------
__global__ void bfill_kernel(const int* __restrict__ dst, const int* __restrict__ srcv,
                             const int* __restrict__ et, const float* __restrict__ W,
                             const float* __restrict__ feat,
                             int* __restrict__ bcnt, int* __restrict__ tmp,
                             unsigned short* __restrict__ WtT,
                             unsigned short* __restrict__ Fb, int E, int N) {
    const int t = threadIdx.x;

    if (blockIdx.x >= NBP) {
        // ------------- Fb rider (+ WtT on first 32 blocks) -------------
        const int fbb = blockIdx.x - NBP;
        if (fbb < 32) {
            int i4 = fbb * 256 + t;           // [0, 8192) float4s of W
            float4 v = ((const float4*)W)[i4];
            int bse = i4 * 4;                 // flat element = (r*64+d)*64 + f
            int f0 = bse & 63;
            int rd = bse >> 6;                // r*64 + d
            int d  = rd & 63;
            int r  = rd >> 6;
            unsigned short* w0 = WtT + ((size_t)(r * 64 + f0) * 64 + d);
            w0[0 * 64] = f2b(v.x);
            w0[1 * 64] = f2b(v.y);
            w0[2 * 64] = f2b(v.z);
            w0[3 * 64] = f2b(v.w);
        }
        const int node = fbb * 64 + (t >> 2);
        if (node >= N) return;
        const int seg = t & 3;
        const float4* F4 = (const float4*)feat + (size_t)node * 16 + seg * 4;
        float4 v0 = F4[0], v1 = F4[1], v2 = F4[2], v3 = F4[3];
        bf16x8 b0, b1;
        b0[0] = (short)f2b(v0.x); b0[1] = (short)f2b(v0.y);
        b0[2] = (short)f2b(v0.z); b0[3] = (short)f2b(v0.w);
        b0[4] = (short)f2b(v1.x); b0[5] = (short)f2b(v1.y);
        b0[6] = (short)f2b(v1.z); b0[7] = (short)f2b(v1.w);
        b1[0] = (short)f2b(v2.x); b1[1] = (short)f2b(v2.y);
        b1[2] = (short)f2b(v2.z); b1[3] = (short)f2b(v2.w);
        b1[4] = (short)f2b(v3.x); b1[5] = (short)f2b(v3.y);
        b1[6] = (short)f2b(v3.z); b1[7] = (short)f2b(v3.w);
        *(bf16x8*)(Fb + (size_t)node * 64 + seg * 16)     = b0;
        *(bf16x8*)(Fb + (size_t)node * 64 + seg * 16 + 8) = b1;
        return;
    }

    // ------------- edge binning half -------------
    __shared__ int hist[NBUCK];
    __shared__ int base[NBUCK];
    __shared__ int lcur[NBUCK];
    for (int j = t; j < NBUCK; j += 256) { hist[j] = 0; lcur[j] = 0; }
    __syncthreads();

    const int4* dst4 = (const int4*)dst;
    const int4* src4 = (const int4*)srcv;
    const int4* et4  = (const int4*)et;
    const int n4 = E >> 2;                    // E % 4 == 0
    int bk[16], pk[16];
#pragma unroll
    for (int k = 0; k < 4; k++) {
        int i4 = blockIdx.x * 1024 + t + k * 256;
        if (i4 < n4) {
            int4 d = dst4[i4];
            int4 s = src4[i4];
            int4 r = et4[i4];
            const int dd[4] = {d.x, d.y, d.z, d.w};
            const int ss[4] = {s.x, s.y, s.z, s.w};
            const int rr[4] = {r.x, r.y, r.z, r.w};
#pragma unroll
            for (int j = 0; j < 4; j++) {
                int idx = k * 4 + j;
                bk[idx] = dd[j] >> 5;
                pk[idx] = (ss[j] & 0xFFFF) | (rr[j] << 16) | ((dd[j] & 31) << 19);
                atomicAdd(&hist[bk[idx]], 1);
            }
        } else {
#pragma unroll
            for (int j = 0; j < 4; j++) bk[k * 4 + j] = -1;
        }
    }
    __syncthreads();
    for (int j = t; j < NBUCK; j += 256)
        if (hist[j] > 0)
            base[j] = j * BCAP + atomicAdd(&bcnt[j], hist[j]);
    __syncthreads();
#pragma unroll
    for (int k = 0; k < 16; k++) {
        if (bk[k] >= 0) {
            int r = atomicAdd(&lcur[bk[k]], 1);
            int pos = base[bk[k]] + r;
            if (pos < (bk[k] + 1) * BCAP)   // memory-safety clamp (never hit)
                tmp[pos] = pk[k];
        }
    }
}

// ---------------------------------------------------------------------------
// Kernel 2: per-block LDS counting sort (256 bins = node*8+rel) -> gather-sum
// (register accumulation per (node,rel) run, pk keys read from LDS broadcast)
// -> per-relation MFMA -> epilogue. No global spk / off arrays at all.
// ---------------------------------------------------------------------------
__global__ __launch_bounds__(256, 4) void fuse_kernel(
    const int* __restrict__ bcnt, const int* __restrict__ tmp,
    const unsigned short* __restrict__ Fb,
    const unsigned short* __restrict__ WtT, const float* __restrict__ feat,
    float* __restrict__ out, int N) {
    __shared__ unsigned short Sb[NRELS][NPB][64];   // 32 KB, swizzled d-blocks
    __shared__ int sedge[BCAP];                     // 3 KB sorted pk
    __shared__ int hist[256];
    __shared__ int noff[NPB + 1];
    const int t = threadIdx.x;
    const int bkt = blockIdx.x;
    const int n0 = bkt * NPB;
    const int nn = min(NPB, N - n0);
    const int gid = t >> 3, q = t & 7;              // group gid = node, lane q = d-block

    // Zero S (covers nodes/rels with no edges).
    {
        f32x4 z = {0.f, 0.f, 0.f, 0.f};
        f32x4* zp = (f32x4*)&Sb[0][0][0];
#pragma unroll
        for (int i = 0; i < 8; i++) zp[t + 256 * i] = z;
    }

    // ---- local counting sort of this bucket by bin = (pk>>16)&255 ----
    const int cnt = min(bcnt[bkt], BCAP);
    const int* tb = tmp + (size_t)bkt * BCAP;
    hist[t] = 0;
    __syncthreads();
    int v0 = (t < cnt) ? tb[t] : -1;                // coalesced bucket read
    int v1 = (t + 256 < cnt) ? tb[t + 256] : -1;
    int v2 = (t + 512 < cnt) ? tb[t + 512] : -1;
    if (v0 >= 0) atomicAdd(&hist[(v0 >> 16) & 255], 1);
    if (v1 >= 0) atomicAdd(&hist[(v1 >> 16) & 255], 1);
    if (v2 >= 0) atomicAdd(&hist[(v2 >> 16) & 255], 1);
    __syncthreads();
    const int myc = hist[t];
    for (int o = 1; o < 256; o <<= 1) {             // inclusive scan, in place
        int u_ = (t >= o) ? hist[t - o] : 0;
        __syncthreads();
        hist[t] += u_;
        __syncthreads();
    }
    const int ex = hist[t] - myc;                   // exclusive start of bin t
    if ((t & 7) == 0) noff[t >> 3] = ex;            // node n starts at bin 8n
    if (t == 255) noff[NPB] = ex + myc;             // = cnt
    __syncthreads();
    hist[t] = ex;
    __syncthreads();
    if (v0 >= 0) { int p = atomicAdd(&hist[(v0 >> 16) & 255], 1); sedge[p] = v0; }
    if (v1 >= 0) { int p = atomicAdd(&hist[(v1 >> 16) & 255], 1); sedge[p] = v1; }
    if (v2 >= 0) { int p = atomicAdd(&hist[(v2 >> 16) & 255], 1); sedge[p] = v2; }
    __syncthreads();

    // ---- gather: group gid owns node n0+gid; lane q owns d-block q.
    int b = 0, e = 0;
    if (gid < nn) { b = noff[gid]; e = noff[gid + 1]; }
    if (gid < nn && b < e) {
        const int swz = (q ^ (gid & 7)) * 8;        // physical slot of logical block q
        unsigned short* srow = &Sb[0][0][0] + (size_t)gid * 64 + swz;
        float a[8] = {0.f, 0.f, 0.f, 0.f, 0.f, 0.f, 0.f, 0.f};
        int curR = -1;

        auto flushS = [&](int rel) {
            bf16x8 v;
#pragma unroll
            for (int k = 0; k < 8; k++) v[k] = (short)f2b(a[k]);
            *(bf16x8*)(srow + (size_t)rel * (NPB * 64)) = v;
        };

        // pk keys from LDS (8 lanes same address -> broadcast, conflict-free).
        int pkj[32];
#pragma unroll
        for (int j = 0; j < 32; j++) pkj[j] = (b + j < e) ? sedge[b + j] : -1;

        // 8-slot ring of independent Fb gathers.
        bf16x8 u[8];
#pragma unroll
        for (int j = 0; j < 8; j++) {
            u[j] = (bf16x8){0, 0, 0, 0, 0, 0, 0, 0};
            if (pkj[j] >= 0)
                u[j] = *(const bf16x8*)(Fb + (size_t)(pkj[j] & 0xFFFF) * 64 + q * 8);
        }
#pragma unroll
        for (int j = 0; j < 32; j++) {
            bf16x8 uu = u[j & 7];
            if (j + 8 < 32 && pkj[j + 8] >= 0)      // refill slot with edge j+8
                u[j & 7] = *(const bf16x8*)(Fb + (size_t)(pkj[j + 8] & 0xFFFF) * 64 + q * 8);
            int pk = pkj[j];
            if (pk >= 0) {
                int rel = (pk >> 16) & 7;
                if (rel != curR) {
                    if (curR >= 0) flushS(curR);
                    curR = rel;
#pragma unroll
                    for (int k = 0; k < 8; k++) a[k] = b2f((unsigned short)uu[k]);
                } else {
#pragma unroll
                    for (int k = 0; k < 8; k++) a[k] += b2f((unsigned short)uu[k]);
                }
            }
        }
        // Rare tail (deg > 32): keys from LDS, cheap.
        for (int i = b + 32; i < e; i++) {
            int pk = sedge[i];
            bf16x8 uu = *(const bf16x8*)(Fb + (size_t)(pk & 0xFFFF) * 64 + q * 8);
            int rel = (pk >> 16) & 7;
            if (rel != curR) {
                if (curR >= 0) flushS(curR);
                curR = rel;
#pragma unroll
                for (int k = 0; k < 8; k++) a[k] = b2f((unsigned short)uu[k]);
            } else {
#pragma unroll
                for (int k = 0; k < 8; k++) a[k] += b2f((unsigned short)uu[k]);
            }
        }
        if (curR >= 0) flushS(curR);
    }

    // Epilogue feat prefetch (hides under MFMA phase).
    float4 h0e = make_float4(0.f, 0.f, 0.f, 0.f), h1e = h0e;
    const int ef0 = q * 8;
    if (gid < nn) {
        const float4* fp = (const float4*)feat + (size_t)(n0 + gid) * 16 + (ef0 >> 2);
        h0e = fp[0];
        h1e = fp[1];
    }
    __syncthreads();

    // ---- MFMA: C[n][f] = sum_r S_r[n][:] @ W_r[:][f]. S is bf16.
    const int w = t >> 6, l = t & 63, col = l & 15, quad = l >> 4;
    f32x4 acc0 = {0.f, 0.f, 0.f, 0.f}, acc1 = {0.f, 0.f, 0.f, 0.f};
    const int sw0 = (quad ^ (col & 7)) * 8;           // logical k-block quad
    const int sw1 = ((quad + 4) ^ (col & 7)) * 8;     // logical k-block quad+4
#pragma unroll
    for (int r = 0; r < NRELS; r++) {
        const unsigned short* wp = WtT + (size_t)r * 4096 + ((w * 16 + col) * 64 + quad * 8);
        bf16x8 b0 = *(const bf16x8*)wp;               // W frags from L2 (hot)
        bf16x8 b1 = *(const bf16x8*)(wp + 32);
        const unsigned short* Sr = &Sb[0][0][0] + (size_t)r * (NPB * 64);
        bf16x8 a0 = *(const bf16x8*)&Sr[col * 64 + sw0];
        bf16x8 a1 = *(const bf16x8*)&Sr[col * 64 + sw1];
        bf16x8 c0 = *(const bf16x8*)&Sr[(16 + col) * 64 + sw0];
        bf16x8 c1 = *(const bf16x8*)&Sr[(16 + col) * 64 + sw1];
        acc0 = __builtin_amdgcn_mfma_f32_16x16x32_bf16(a0, b0, acc0, 0, 0, 0);
        acc0 = __builtin_amdgcn_mfma_f32_16x16x32_bf16(a1, b1, acc0, 0, 0, 0);
        acc1 = __builtin_amdgcn_mfma_f32_16x16x32_bf16(c0, b0, acc1, 0, 0, 0);
        acc1 = __builtin_amdgcn_mfma_f32_16x16x32_bf16(c1, b1, acc1, 0, 0, 0);
    }
    __syncthreads();   // all S reads done -> alias Sb as C bounce [32][72] f32

    float* C = (float*)&Sb[0][0][0];
#pragma unroll
    for (int i = 0; i < 4; i++) {
        C[(quad * 4 + i) * 72 + w * 16 + col]        = acc0[i];
        C[(16 + quad * 4 + i) * 72 + w * 16 + col]   = acc1[i];
    }
    __syncthreads();

    // ---- epilogue: thread t -> node gid (= t>>3), f-block q (coalesced).
    if (gid < nn) {
        const int gn = n0 + gid;
        const int deg = e - b;
        float4 m0 = *(const float4*)&C[gid * 72 + ef0];
        float4 m1 = *(const float4*)&C[gid * 72 + ef0 + 4];
        float4 r0, r1;
        if (deg > 0) {
            float inv = 0.8f / (float)deg;
            r0.x = fmaxf(0.2f * h0e.x + m0.x * inv, 0.f);
            r0.y = fmaxf(0.2f * h0e.y + m0.y * inv, 0.f);
            r0.z = fmaxf(0.2f * h0e.z + m0.z * inv, 0.f);
            r0.w = fmaxf(0.2f * h0e.w + m0.w * inv, 0.f);
            r1.x = fmaxf(0.2f * h1e.x + m1.x * inv, 0.f);
            r1.y = fmaxf(0.2f * h1e.y + m1.y * inv, 0.f);
            r1.z = fmaxf(0.2f * h1e.z + m1.z * inv, 0.f);
            r1.w = fmaxf(0.2f * h1e.w + m1.w * inv, 0.f);
        } else {
            r0 = h0e; r1 = h1e;
        }
        float4* op = (float4*)out + (size_t)gn * 16 + (ef0 >> 2);
        op[0] = r0;
        op[1] = r1;
    }
}

// ---------------------------------------------------------------------------
// Fallback kernels (small workspace): on-the-fly transform + atomics (fp32).
// ---------------------------------------------------------------------------
__global__ void degf_kernel(const int* __restrict__ dst, float* __restrict__ deg, int E) {
    int e = blockIdx.x * blockDim.x + threadIdx.x;
    if (e < E) atomicAdd(deg + dst[e], 1.0f);
}

__global__ void otf_kernel(const int* __restrict__ src, const int* __restrict__ dst,
                           const int* __restrict__ et, const float* __restrict__ feat,
                           const float* __restrict__ W, float* __restrict__ out, int E) {
    int wid = (blockIdx.x * blockDim.x + threadIdx.x) >> 6;
    int l = threadIdx.x & 63;
    if (wid >= E) return;
    int s = src[wid], dd = dst[wid], r = et[wid];
    float fv = feat[(size_t)s * 64 + l];
    const float* Wr = W + (size_t)r * 4096;
    float acc = 0.f;
#pragma unroll
    for (int d = 0; d < 64; d++) {
        float a = __shfl(fv, d);
        acc += a * Wr[d * 64 + l];
    }
    atomicAdd(out + (size_t)dd * 64 + l, acc);
}

__global__ void final_kernel(const float* __restrict__ feat, const float* __restrict__ deg,
                             float* __restrict__ out, int N) {
    int i = blockIdx.x * blockDim.x + threadIdx.x;
    if (i >= N * 16) return;
    int n = i >> 4;
    float d = deg[n];
    float4 f = ((const float4*)feat)[i];
    float4 m = ((float4*)out)[i];
    float4 res;
    if (d > 0.f) {
        float inv = 0.8f / d;
        res.x = fmaxf(0.2f * f.x + m.x * inv, 0.f);
        res.y = fmaxf(0.2f * f.y + m.y * inv, 0.f);
        res.z = fmaxf(0.2f * f.z + m.z * inv, 0.f);
        res.w = fmaxf(0.2f * f.w + m.w * inv, 0.f);
    } else {
        res = f;
    }
    ((float4*)out)[i] = res;
}

extern "C" void kernel_launch(void* const* d_in, const int* in_sizes, int n_in,
                              void* d_out, int out_size, void* d_ws, size_t ws_size,
                              hipStream_t stream) {
    const float* feat = (const float*)d_in[0];   // [N, 64]
    const float* W    = (const float*)d_in[1];   // [8, 64, 64]
    const int*   src  = (const int*)d_in[2];     // [E]
    const int*   dst  = (const int*)d_in[3];     // [E]
    const int*   et   = (const int*)d_in[4];     // [E]
    float* out = (float*)d_out;                  // [N, 64]

    const int N = N_NODES, E = N_EDGES;

    // Workspace layout:
    char* p = (char*)d_ws;
    int* bcnt  = (int*)p;  p += align256((size_t)NBUCK * 4);          // 6.3 KB
    int* tmp   = (int*)p;  p += align256((size_t)NBUCK * BCAP * 4);   // 4.6 MB
    unsigned short* WtT = (unsigned short*)p;
    p += align256((size_t)NRELS * FEAT * FEAT * 2);                   // 64 KB
    unsigned short* Fb = (unsigned short*)p;
    p += align256((size_t)N * FEAT * 2);                              // 6.4 MB
    size_t need_full = (size_t)(p - (char*)d_ws);

    if (ws_size >= need_full) {
        hipMemsetAsync(bcnt, 0, (size_t)NBUCK * 4, stream);
        bfill_kernel<<<NBP + FB_BLOCKS, 256, 0, stream>>>(dst, src, et, W, feat,
                                                          bcnt, tmp, WtT, Fb, E, N);
        fuse_kernel<<<NBUCK, 256, 0, stream>>>(bcnt, tmp, Fb, WtT, feat, out, N);
    } else {
        // Minimal-workspace fallback.
        float* deg = (float*)d_ws;
        hipMemsetAsync(out, 0, (size_t)N * FEAT * 4, stream);
        hipMemsetAsync(deg, 0, (size_t)N * 4, stream);
        degf_kernel<<<(E + 255) / 256, 256, 0, stream>>>(dst, deg, E);
        otf_kernel<<<(E + 3) / 4, 256, 0, stream>>>(src, dst, et, feat, W, out, E);
        final_kernel<<<(N * 16 + 255) / 256, 256, 0, stream>>>(feat, deg, out, N);
    }
}

// Round 7
// 122.767 us; speedup vs baseline: 1.0582x; 1.0179x over previous
//
#include <hip/hip_runtime.h>
#include <hip/hip_bf16.h>

#define N_NODES 50000
#define N_EDGES 800000
#define FEAT 64
#define NRELS 8
#define NPB 32            // dst nodes per bucket = per fuse block
#define NBUCK 1563        // ceil(50000/32) buckets (dst >> 5)
#define NBP 196           // bfill binning blocks (4096 edges each)
#define BCAP 768          // slots per bucket (mean 512 + 11 sigma)
#define FB_BLOCKS 782     // ceil(N / 64) feat->bf16 rider blocks (in bfill)

typedef __attribute__((ext_vector_type(8))) short bf16x8;   // 8 bf16 in 4 VGPRs
typedef __attribute__((ext_vector_type(4))) float f32x4;

static __host__ __device__ inline size_t align256(size_t x) { return (x + 255) & ~(size_t)255; }

__device__ inline unsigned short f2b(float f) {   // fp32 -> bf16 RNE
    unsigned u = __builtin_bit_cast(unsigned, f);
    unsigned r = (u + 0x7fffu + ((u >> 16) & 1u)) >> 16;
    return (unsigned short)r;
}
__device__ inline float b2f(unsigned short u) {   // bf16 -> fp32
    unsigned v = ((unsigned)u) << 16;
    return __builtin_bit_cast(float, v);
}

// ---------------------------------------------------------------------------
// Kernel 1: blocks [0,NBP) = bin edges into 32-node buckets (bucket = dst>>5,
// entry pk = src | et<<16 | (dst&31)<<19 -> sort key (pk>>16)&255 = node*8+rel);
// blocks [NBP, NBP+FB_BLOCKS) = feat->bf16 (Fb) rider; first 32 riders also
// build WtT[r][f][d] = bf16(W[r][d][f]).
// ---------------------------------------------------------------------------
__global__ void bfill_kernel(const int* __restrict__ dst, const int* __restrict__ srcv,
                             const int* __restrict__ et, const float* __restrict__ W,
                             const float* __restrict__ feat,
                             int* __restrict__ bcnt, int* __restrict__ tmp,
                             unsigned short* __restrict__ WtT,
                             unsigned short* __restrict__ Fb, int E, int N) {
    const int t = threadIdx.x;

    if (blockIdx.x >= NBP) {
        // ------------- Fb rider (+ WtT on first 32 blocks) -------------
        const int fbb = blockIdx.x - NBP;
        if (fbb < 32) {
            int i4 = fbb * 256 + t;           // [0, 8192) float4s of W
            float4 v = ((const float4*)W)[i4];
            int bse = i4 * 4;                 // flat element = (r*64+d)*64 + f
            int f0 = bse & 63;
            int rd = bse >> 6;                // r*64 + d
            int d  = rd & 63;
            int r  = rd >> 6;
            unsigned short* w0 = WtT + ((size_t)(r * 64 + f0) * 64 + d);
            w0[0 * 64] = f2b(v.x);
            w0[1 * 64] = f2b(v.y);
            w0[2 * 64] = f2b(v.z);
            w0[3 * 64] = f2b(v.w);
        }
        const int node = fbb * 64 + (t >> 2);
        if (node >= N) return;
        const int seg = t & 3;
        const float4* F4 = (const float4*)feat + (size_t)node * 16 + seg * 4;
        float4 v0 = F4[0], v1 = F4[1], v2 = F4[2], v3 = F4[3];
        bf16x8 b0, b1;
        b0[0] = (short)f2b(v0.x); b0[1] = (short)f2b(v0.y);
        b0[2] = (short)f2b(v0.z); b0[3] = (short)f2b(v0.w);
        b0[4] = (short)f2b(v1.x); b0[5] = (short)f2b(v1.y);
        b0[6] = (short)f2b(v1.z); b0[7] = (short)f2b(v1.w);
        b1[0] = (short)f2b(v2.x); b1[1] = (short)f2b(v2.y);
        b1[2] = (short)f2b(v2.z); b1[3] = (short)f2b(v2.w);
        b1[4] = (short)f2b(v3.x); b1[5] = (short)f2b(v3.y);
        b1[6] = (short)f2b(v3.z); b1[7] = (short)f2b(v3.w);
        *(bf16x8*)(Fb + (size_t)node * 64 + seg * 16)     = b0;
        *(bf16x8*)(Fb + (size_t)node * 64 + seg * 16 + 8) = b1;
        return;
    }

    // ------------- edge binning half -------------
    __shared__ int hist[NBUCK];
    __shared__ int base[NBUCK];
    __shared__ int lcur[NBUCK];
    for (int j = t; j < NBUCK; j += 256) { hist[j] = 0; lcur[j] = 0; }
    __syncthreads();

    const int4* dst4 = (const int4*)dst;
    const int4* src4 = (const int4*)srcv;
    const int4* et4  = (const int4*)et;
    const int n4 = E >> 2;                    // E % 4 == 0
    int bk[16], pk[16];
#pragma unroll
    for (int k = 0; k < 4; k++) {
        int i4 = blockIdx.x * 1024 + t + k * 256;
        if (i4 < n4) {
            int4 d = dst4[i4];
            int4 s = src4[i4];
            int4 r = et4[i4];
            const int dd[4] = {d.x, d.y, d.z, d.w};
            const int ss[4] = {s.x, s.y, s.z, s.w};
            const int rr[4] = {r.x, r.y, r.z, r.w};
#pragma unroll
            for (int j = 0; j < 4; j++) {
                int idx = k * 4 + j;
                bk[idx] = dd[j] >> 5;
                pk[idx] = (ss[j] & 0xFFFF) | (rr[j] << 16) | ((dd[j] & 31) << 19);
                atomicAdd(&hist[bk[idx]], 1);
            }
        } else {
#pragma unroll
            for (int j = 0; j < 4; j++) bk[k * 4 + j] = -1;
        }
    }
    __syncthreads();
    for (int j = t; j < NBUCK; j += 256)
        if (hist[j] > 0)
            base[j] = j * BCAP + atomicAdd(&bcnt[j], hist[j]);
    __syncthreads();
#pragma unroll
    for (int k = 0; k < 16; k++) {
        if (bk[k] >= 0) {
            int r = atomicAdd(&lcur[bk[k]], 1);
            int pos = base[bk[k]] + r;
            if (pos < (bk[k] + 1) * BCAP)   // memory-safety clamp (never hit)
                tmp[pos] = pk[k];
        }
    }
}

// ---------------------------------------------------------------------------
// Kernel 2: per-block LDS counting sort (256 bins = node*8+rel, wave-shuffle
// scan, 4 barriers) -> gather-sum with chunked double-buffered Fb loads
// pinned by sched_barrier(0) (8 loads in flight across the consume phase)
// -> per-relation MFMA -> epilogue.
// ---------------------------------------------------------------------------
__global__ __launch_bounds__(256, 4) void fuse_kernel(
    const int* __restrict__ bcnt, const int* __restrict__ tmp,
    const unsigned short* __restrict__ Fb,
    const unsigned short* __restrict__ WtT, const float* __restrict__ feat,
    float* __restrict__ out, int N) {
    __shared__ unsigned short Sb[NRELS][NPB][64];   // 32 KB, swizzled d-blocks
    __shared__ int sedge[BCAP];                     // 3 KB sorted pk
    __shared__ int hist[256];
    __shared__ int noff[NPB + 1];
    __shared__ int wsum[4];
    const int t = threadIdx.x;
    const int bkt = blockIdx.x;
    const int n0 = bkt * NPB;
    const int nn = min(NPB, N - n0);
    const int gid = t >> 3, q = t & 7;              // group gid = node, lane q = d-block

    // Zero S (covers nodes/rels with no edges) + hist.
    {
        f32x4 z = {0.f, 0.f, 0.f, 0.f};
        f32x4* zp = (f32x4*)&Sb[0][0][0];
#pragma unroll
        for (int i = 0; i < 8; i++) zp[t + 256 * i] = z;
    }
    hist[t] = 0;
    __syncthreads();

    // ---- local counting sort of this bucket by bin = (pk>>16)&255 ----
    const int cnt = min(bcnt[bkt], BCAP);
    const int* tb = tmp + (size_t)bkt * BCAP;
    int v0 = (t < cnt) ? tb[t] : -1;                // coalesced bucket read
    int v1 = (t + 256 < cnt) ? tb[t + 256] : -1;
    int v2 = (t + 512 < cnt) ? tb[t + 512] : -1;
    if (v0 >= 0) atomicAdd(&hist[(v0 >> 16) & 255], 1);
    if (v1 >= 0) atomicAdd(&hist[(v1 >> 16) & 255], 1);
    if (v2 >= 0) atomicAdd(&hist[(v2 >> 16) & 255], 1);
    __syncthreads();
    const int myc = hist[t];
    // wave-level inclusive scan (no barriers inside a wave)
    int x = myc;
#pragma unroll
    for (int o = 1; o < 64; o <<= 1) {
        int u_ = __shfl_up(x, o);
        if ((t & 63) >= o) x += u_;
    }
    if ((t & 63) == 63) wsum[t >> 6] = x;
    __syncthreads();
    {
        int add = 0;
        const int wv = t >> 6;
        if (wv > 0) add += wsum[0];
        if (wv > 1) add += wsum[1];
        if (wv > 2) add += wsum[2];
        x += add;
    }
    const int ex = x - myc;                         // exclusive start of bin t
    if ((t & 7) == 0) noff[t >> 3] = ex;            // node n starts at bin 8n
    if (t == 255) noff[NPB] = ex + myc;             // = cnt
    hist[t] = ex;
    __syncthreads();
    if (v0 >= 0) { int p = atomicAdd(&hist[(v0 >> 16) & 255], 1); sedge[p] = v0; }
    if (v1 >= 0) { int p = atomicAdd(&hist[(v1 >> 16) & 255], 1); sedge[p] = v1; }
    if (v2 >= 0) { int p = atomicAdd(&hist[(v2 >> 16) & 255], 1); sedge[p] = v2; }
    __syncthreads();

    // ---- gather: group gid owns node n0+gid; lane q owns d-block q.
    int b = 0, e = 0;
    if (gid < nn) { b = noff[gid]; e = noff[gid + 1]; }
    if (gid < nn && b < e) {
        const int swz = (q ^ (gid & 7)) * 8;        // physical slot of logical block q
        unsigned short* srow = &Sb[0][0][0] + (size_t)gid * 64 + swz;
        float a[8] = {0.f, 0.f, 0.f, 0.f, 0.f, 0.f, 0.f, 0.f};
        int curR = -1;

        auto flushS = [&](int rel) {
            bf16x8 v;
#pragma unroll
            for (int k = 0; k < 8; k++) v[k] = (short)f2b(a[k]);
            *(bf16x8*)(srow + (size_t)rel * (NPB * 64)) = v;
        };

        // Chunked double-buffer: 8 independent Fb loads in flight, pinned by
        // sched_barrier(0) so the compiler cannot sink them to their uses.
        int pkc[2][8];
        bf16x8 uc[2][8];
#pragma unroll
        for (int j = 0; j < 8; j++) {               // preload chunk 0
            int pk = (b + j < e) ? sedge[b + j] : -1;
            pkc[0][j] = pk;
            uc[0][j] = (bf16x8){0, 0, 0, 0, 0, 0, 0, 0};
            if (pk >= 0)
                uc[0][j] = *(const bf16x8*)(Fb + (size_t)(pk & 0xFFFF) * 64 + q * 8);
        }
        __builtin_amdgcn_sched_barrier(0);
#pragma unroll
        for (int c = 0; c < 4; c++) {
            const int cur = c & 1, nxt = (c & 1) ^ 1;
            if (c < 3) {                            // issue chunk c+1 loads
                const int cb = b + (c + 1) * 8;
#pragma unroll
                for (int j = 0; j < 8; j++) {
                    int pk = (cb + j < e) ? sedge[cb + j] : -1;
                    pkc[nxt][j] = pk;
                    uc[nxt][j] = (bf16x8){0, 0, 0, 0, 0, 0, 0, 0};
                    if (pk >= 0)
                        uc[nxt][j] = *(const bf16x8*)(Fb + (size_t)(pk & 0xFFFF) * 64 + q * 8);
                }
            }
            __builtin_amdgcn_sched_barrier(0);
            // consume chunk c
#pragma unroll
            for (int j = 0; j < 8; j++) {
                int pk = pkc[cur][j];
                if (pk >= 0) {
                    bf16x8 uu = uc[cur][j];
                    int rel = (pk >> 16) & 7;
                    if (rel != curR) {
                        if (curR >= 0) flushS(curR);
                        curR = rel;
#pragma unroll
                        for (int k = 0; k < 8; k++) a[k] = b2f((unsigned short)uu[k]);
                    } else {
#pragma unroll
                        for (int k = 0; k < 8; k++) a[k] += b2f((unsigned short)uu[k]);
                    }
                }
            }
            if (b + (c + 1) * 8 >= e) break;        // group-uniform early exit
        }
        // Rare tail (deg > 32): keys from LDS, serial.
        for (int i = b + 32; i < e; i++) {
            int pk = sedge[i];
            bf16x8 uu = *(const bf16x8*)(Fb + (size_t)(pk & 0xFFFF) * 64 + q * 8);
            int rel = (pk >> 16) & 7;
            if (rel != curR) {
                if (curR >= 0) flushS(curR);
                curR = rel;
#pragma unroll
                for (int k = 0; k < 8; k++) a[k] = b2f((unsigned short)uu[k]);
            } else {
#pragma unroll
                for (int k = 0; k < 8; k++) a[k] += b2f((unsigned short)uu[k]);
            }
        }
        if (curR >= 0) flushS(curR);
    }

    // Epilogue feat prefetch (hides under MFMA phase).
    float4 h0e = make_float4(0.f, 0.f, 0.f, 0.f), h1e = h0e;
    const int ef0 = q * 8;
    if (gid < nn) {
        const float4* fp = (const float4*)feat + (size_t)(n0 + gid) * 16 + (ef0 >> 2);
        h0e = fp[0];
        h1e = fp[1];
    }
    __syncthreads();

    // ---- MFMA: C[n][f] = sum_r S_r[n][:] @ W_r[:][f]. S is bf16.
    const int w = t >> 6, l = t & 63, col = l & 15, quad = l >> 4;
    f32x4 acc0 = {0.f, 0.f, 0.f, 0.f}, acc1 = {0.f, 0.f, 0.f, 0.f};
    const int sw0 = (quad ^ (col & 7)) * 8;           // logical k-block quad
    const int sw1 = ((quad + 4) ^ (col & 7)) * 8;     // logical k-block quad+4
#pragma unroll
    for (int r = 0; r < NRELS; r++) {
        const unsigned short* wp = WtT + (size_t)r * 4096 + ((w * 16 + col) * 64 + quad * 8);
        bf16x8 b0 = *(const bf16x8*)wp;               // W frags from L2 (hot)
        bf16x8 b1 = *(const bf16x8*)(wp + 32);
        const unsigned short* Sr = &Sb[0][0][0] + (size_t)r * (NPB * 64);
        bf16x8 a0 = *(const bf16x8*)&Sr[col * 64 + sw0];
        bf16x8 a1 = *(const bf16x8*)&Sr[col * 64 + sw1];
        bf16x8 c0 = *(const bf16x8*)&Sr[(16 + col) * 64 + sw0];
        bf16x8 c1 = *(const bf16x8*)&Sr[(16 + col) * 64 + sw1];
        acc0 = __builtin_amdgcn_mfma_f32_16x16x32_bf16(a0, b0, acc0, 0, 0, 0);
        acc0 = __builtin_amdgcn_mfma_f32_16x16x32_bf16(a1, b1, acc0, 0, 0, 0);
        acc1 = __builtin_amdgcn_mfma_f32_16x16x32_bf16(c0, b0, acc1, 0, 0, 0);
        acc1 = __builtin_amdgcn_mfma_f32_16x16x32_bf16(c1, b1, acc1, 0, 0, 0);
    }
    __syncthreads();   // all S reads done -> alias Sb as C bounce [32][72] f32

    float* C = (float*)&Sb[0][0][0];
#pragma unroll
    for (int i = 0; i < 4; i++) {
        C[(quad * 4 + i) * 72 + w * 16 + col]        = acc0[i];
        C[(16 + quad * 4 + i) * 72 + w * 16 + col]   = acc1[i];
    }
    __syncthreads();

    // ---- epilogue: thread t -> node gid (= t>>3), f-block q (coalesced).
    if (gid < nn) {
        const int gn = n0 + gid;
        const int deg = e - b;
        float4 m0 = *(const float4*)&C[gid * 72 + ef0];
        float4 m1 = *(const float4*)&C[gid * 72 + ef0 + 4];
        float4 r0, r1;
        if (deg > 0) {
            float inv = 0.8f / (float)deg;
            r0.x = fmaxf(0.2f * h0e.x + m0.x * inv, 0.f);
            r0.y = fmaxf(0.2f * h0e.y + m0.y * inv, 0.f);
            r0.z = fmaxf(0.2f * h0e.z + m0.z * inv, 0.f);
            r0.w = fmaxf(0.2f * h0e.w + m0.w * inv, 0.f);
            r1.x = fmaxf(0.2f * h1e.x + m1.x * inv, 0.f);
            r1.y = fmaxf(0.2f * h1e.y + m1.y * inv, 0.f);
            r1.z = fmaxf(0.2f * h1e.z + m1.z * inv, 0.f);
            r1.w = fmaxf(0.2f * h1e.w + m1.w * inv, 0.f);
        } else {
            r0 = h0e; r1 = h1e;
        }
        float4* op = (float4*)out + (size_t)gn * 16 + (ef0 >> 2);
        op[0] = r0;
        op[1] = r1;
    }
}

// ---------------------------------------------------------------------------
// Fallback kernels (small workspace): on-the-fly transform + atomics (fp32).
// ---------------------------------------------------------------------------
__global__ void degf_kernel(const int* __restrict__ dst, float* __restrict__ deg, int E) {
    int e = blockIdx.x * blockDim.x + threadIdx.x;
    if (e < E) atomicAdd(deg + dst[e], 1.0f);
}

__global__ void otf_kernel(const int* __restrict__ src, const int* __restrict__ dst,
                           const int* __restrict__ et, const float* __restrict__ feat,
                           const float* __restrict__ W, float* __restrict__ out, int E) {
    int wid = (blockIdx.x * blockDim.x + threadIdx.x) >> 6;
    int l = threadIdx.x & 63;
    if (wid >= E) return;
    int s = src[wid], dd = dst[wid], r = et[wid];
    float fv = feat[(size_t)s * 64 + l];
    const float* Wr = W + (size_t)r * 4096;
    float acc = 0.f;
#pragma unroll
    for (int d = 0; d < 64; d++) {
        float a = __shfl(fv, d);
        acc += a * Wr[d * 64 + l];
    }
    atomicAdd(out + (size_t)dd * 64 + l, acc);
}

__global__ void final_kernel(const float* __restrict__ feat, const float* __restrict__ deg,
                             float* __restrict__ out, int N) {
    int i = blockIdx.x * blockDim.x + threadIdx.x;
    if (i >= N * 16) return;
    int n = i >> 4;
    float d = deg[n];
    float4 f = ((const float4*)feat)[i];
    float4 m = ((float4*)out)[i];
    float4 res;
    if (d > 0.f) {
        float inv = 0.8f / d;
        res.x = fmaxf(0.2f * f.x + m.x * inv, 0.f);
        res.y = fmaxf(0.2f * f.y + m.y * inv, 0.f);
        res.z = fmaxf(0.2f * f.z + m.z * inv, 0.f);
        res.w = fmaxf(0.2f * f.w + m.w * inv, 0.f);
    } else {
        res = f;
    }
    ((float4*)out)[i] = res;
}

extern "C" void kernel_launch(void* const* d_in, const int* in_sizes, int n_in,
                              void* d_out, int out_size, void* d_ws, size_t ws_size,
                              hipStream_t stream) {
    const float* feat = (const float*)d_in[0];   // [N, 64]
    const float* W    = (const float*)d_in[1];   // [8, 64, 64]
    const int*   src  = (const int*)d_in[2];     // [E]
    const int*   dst  = (const int*)d_in[3];     // [E]
    const int*   et   = (const int*)d_in[4];     // [E]
    float* out = (float*)d_out;                  // [N, 64]

    const int N = N_NODES, E = N_EDGES;

    // Workspace layout:
    char* p = (char*)d_ws;
    int* bcnt  = (int*)p;  p += align256((size_t)NBUCK * 4);          // 6.3 KB
    int* tmp   = (int*)p;  p += align256((size_t)NBUCK * BCAP * 4);   // 4.6 MB
    unsigned short* WtT = (unsigned short*)p;
    p += align256((size_t)NRELS * FEAT * FEAT * 2);                   // 64 KB
    unsigned short* Fb = (unsigned short*)p;
    p += align256((size_t)N * FEAT * 2);                              // 6.4 MB
    size_t need_full = (size_t)(p - (char*)d_ws);

    if (ws_size >= need_full) {
        hipMemsetAsync(bcnt, 0, (size_t)NBUCK * 4, stream);
        bfill_kernel<<<NBP + FB_BLOCKS, 256, 0, stream>>>(dst, src, et, W, feat,
                                                          bcnt, tmp, WtT, Fb, E, N);
        fuse_kernel<<<NBUCK, 256, 0, stream>>>(bcnt, tmp, Fb, WtT, feat, out, N);
    } else {
        // Minimal-workspace fallback.
        float* deg = (float*)d_ws;
        hipMemsetAsync(out, 0, (size_t)N * FEAT * 4, stream);
        hipMemsetAsync(deg, 0, (size_t)N * 4, stream);
        degf_kernel<<<(E + 255) / 256, 256, 0, stream>>>(dst, deg, E);
        otf_kernel<<<(E + 3) / 4, 256, 0, stream>>>(src, dst, et, feat, W, out, E);
        final_kernel<<<(N * 16 + 255) / 256, 256, 0, stream>>>(feat, deg, out, N);
    }
}